// Round 4
// baseline (307.653 us; speedup 1.0000x reference)
//
#include <hip/hip_runtime.h>
#include <math.h>

// Problem shape (fixed by the bench's setup_inputs)
#define NS 16384
#define ND 2048
#define NC 1000
#define NCPAD 1024

typedef _Float16 f16x8 __attribute__((ext_vector_type(8)));
typedef _Float16 f16x4 __attribute__((ext_vector_type(4)));
typedef __fp16   h16x2 __attribute__((ext_vector_type(2)));
typedef float f32x4  __attribute__((ext_vector_type(4)));

// Candidate window: must exceed 2*E where E bounds |approx - exact| per score.
// E <= 10-sigma of sum-of-2048 f16-product errors (~0.44) + f16 store round
// (<=0.11) => 2E ~ 1.1.  Delta = 2.5 gives >2x margin.
#define DELTA 2.5f

// Fast path: mhi 4MB + xh 64MB + sc 32MB = 100 MB
#define WS_NEW 104857600ull
// Mid-tier path: mhi 4MB + sc 32MB
#define WS_MID 37748736ull

__device__ __forceinline__ void gl_lds16_h(const _Float16* g, _Float16* l) {
    __builtin_amdgcn_global_load_lds(
        (const __attribute__((address_space(1))) unsigned int*)g,
        (__attribute__((address_space(3))) unsigned int*)l, 16, 0, 0);
}
__device__ __forceinline__ void gl_lds16_f(const float* g, float* l) {
    __builtin_amdgcn_global_load_lds(
        (const __attribute__((address_space(1))) unsigned int*)g,
        (__attribute__((address_space(3))) unsigned int*)l, 16, 0, 0);
}

// fp32x8 -> f16x8 (RTZ pack) — used only by the mid-tier fallback GEMM
__device__ __forceinline__ f16x8 cvt8(const f32x4 a0, const f32x4 a1) {
    const h16x2 h01 = __builtin_amdgcn_cvt_pkrtz(a0[0], a0[1]);
    const h16x2 h23 = __builtin_amdgcn_cvt_pkrtz(a0[2], a0[3]);
    const h16x2 h45 = __builtin_amdgcn_cvt_pkrtz(a1[0], a1[1]);
    const h16x2 h67 = __builtin_amdgcn_cvt_pkrtz(a1[2], a1[3]);
    f16x8 h;
    h[0]=(_Float16)h01[0]; h[1]=(_Float16)h01[1]; h[2]=(_Float16)h23[0]; h[3]=(_Float16)h23[1];
    h[4]=(_Float16)h45[0]; h[5]=(_Float16)h45[1]; h[6]=(_Float16)h67[0]; h[7]=(_Float16)h67[1];
    return h;
}

// ---- kernel 1: fused fp32->f16 (RN) conversion of means (zero-padded to
// NCPAD rows) AND x.  Pure-BW kernel, ~207 MB traffic. ----------------------
__global__ __launch_bounds__(256)
void cvt_all_kernel(const float* __restrict__ x, const float* __restrict__ means,
                    _Float16* __restrict__ xh, _Float16* __restrict__ mhi)
{
    const size_t i = (size_t)blockIdx.x * 256 + threadIdx.x;  // float4 slot
    const size_t NM4 = (size_t)NCPAD * ND / 4;                // 524288
    if (i < NM4) {
        const int row = (int)(i >> 9);                        // (i*4)/ND
        float4 v = make_float4(0.f, 0.f, 0.f, 0.f);
        if (row < NC) v = ((const float4*)means)[i];
        f16x4 h;
        h[0]=(_Float16)v.x; h[1]=(_Float16)v.y; h[2]=(_Float16)v.z; h[3]=(_Float16)v.w;
        ((f16x4*)mhi)[i] = h;
    } else {
        const size_t j = i - NM4;                             // < NS*ND/4
        const float4 v = ((const float4*)x)[j];
        f16x4 h;
        h[0]=(_Float16)v.x; h[1]=(_Float16)v.y; h[2]=(_Float16)v.z; h[3]=(_Float16)v.w;
        ((f16x4*)xh)[j] = h;
    }
}

// ============================================================================
// kernel 2: 256x256 8-phase deep-pipelined f16 MFMA GEMM (T2+T3+T4+T5 port).
//
// BM=BN=256, BK=64 split as 2 K-halves of 32; 512 threads = 8 waves (2M x 4N),
// wave tile 128x64 -> acc[8][4].  LDS = 2(par) x 2(kk) x 256x32 f16 per
// operand = 128 KiB.  Per K-tile: 4 phases, each {ds_read subtile; issue ONE
// stage unit (2 gl_lds, one K-half of one operand of a future tile);
// SINGLE vmcnt(4) per K-tile at phase 3 only (T4: never drain, one counted
// wait per tile); barrier; lgkmcnt(0); setprio(1); 16 MFMA; setprio(0);
// barrier}.
//
// Stage stream (tile t): p0 -> (t+1).A.kk1 | p1 -> (t+1).B.kk1 |
//                        p2 -> (t+2).A.kk0 | p3 -> (t+2).B.kk0
// Prologue primes: 0Ak0,0Bk0,0Ak1,0Bk1,1Ak0,1Bk0 then vmcnt(4) (= tile 0
// fully resident; 2 units outstanding, matching steady state).
// Single-wait hazard ledger (units, 2 loads each, oldest->newest at t.p3):
//   (t-1).p2[(t+1)Ak0], (t-1).p3[(t+1)Bk0], t.p0[(t+1)Ak1], t.p1[(t+1)Bk1],
//   t.p2[(t+2)Ak0], t.p3[(t+2)Bk0]  = 12 loads; vmcnt(4) completes the 4
//   oldest units = ALL of tile t+1 (kk0+kk1) before the barrier opening t+1.
// WAR safety: each stage target's last ds_read completed >= 1 lgkmcnt(0) +
//   barrier before the stage issues (kk0 dead after p1, kk1 dead after p3,
//   parity alternates buffers).
// Tail: stage source tile CLAMPED to 31 -> counts stay uniform; clamped
// stages land only in dead regions (never read again).
// Fragment/epilogue layout identical to the r1/r2-verified kernel.
// ============================================================================
__device__ __forceinline__ void stage_unit(const _Float16* __restrict__ src,
                                           size_t g0, _Float16* dstbase,
                                           int ktile, int kkh, int tid)
{
    const int srcT = ktile < 31 ? ktile : 31;   // clamp: dead-region safe
#pragma unroll
    for (int q = 0; q < 2; ++q) {
        const int slot = q * 512 + tid;          // 0..1023 (16B chunks)
        const int row  = slot >> 2;              // 0..255
        const int g    = (slot & 3) ^ ((row >> 1) & 3);
        gl_lds16_h(src + ((g0 + (size_t)row) << 11) + srcT * 64 + kkh * 32 + g * 8,
                   dstbase + (size_t)(q * 512 + ((tid >> 6) << 6)) * 8);
    }
}

__global__ __launch_bounds__(512, 1)
void gemm256_kernel(const _Float16* __restrict__ xh,
                    const _Float16* __restrict__ mhi,
                    _Float16* __restrict__ sc)
{
    __shared__ _Float16 sA[2][2][256 * 32];   // [par][kk] 64 KB
    __shared__ _Float16 sB[2][2][256 * 32];   // 64 KB

    const int tid  = threadIdx.x;
    const int lane = tid & 63;
    const int w    = tid >> 6;           // 0..7
    const int wm   = w >> 2;             // 0..1 (M half)
    const int wn   = w & 3;              // 0..3 (N quarter)
    const int quad = lane >> 4, l16 = lane & 15;

    // XCD-bijective swizzle: grid (4,64) -> 256 blocks, 32 per XCD,
    // each XCD gets 8 contiguous row-panels x all 4 col-tiles.
    const int orig = blockIdx.x + (blockIdx.y << 2);
    const int nid  = ((orig & 7) << 5) + (orig >> 3);
    const size_t gm0 = (size_t)(nid >> 2) * 256;   // sample rows
    const size_t gn0 = (size_t)(nid & 3) * 256;    // class cols

    f32x4 acc[8][4] = {};

    // prologue: ages must match steady stream
    stage_unit(xh,  gm0, &sA[0][0][0], 0, 0, tid);
    stage_unit(mhi, gn0, &sB[0][0][0], 0, 0, tid);
    stage_unit(xh,  gm0, &sA[0][1][0], 0, 1, tid);
    stage_unit(mhi, gn0, &sB[0][1][0], 0, 1, tid);
    stage_unit(xh,  gm0, &sA[1][0][0], 1, 0, tid);
    stage_unit(mhi, gn0, &sB[1][0][0], 1, 0, tid);
    asm volatile("s_waitcnt vmcnt(4)" ::: "memory");
    __builtin_amdgcn_s_barrier();

    f16x8 b[4];
    for (int kt = 0; kt < 32; ++kt) {
        const int par = kt & 1;
#pragma unroll
        for (int p = 0; p < 4; ++p) {
            const int mh = p & 1, kk = p >> 1;

            f16x8 a[4];
#pragma unroll
            for (int i = 0; i < 4; ++i) {
                const int ar = wm * 128 + mh * 64 + i * 16 + l16;
                const int pc = quad ^ ((ar >> 1) & 3);
                a[i] = *(const f16x8*)&sA[par][kk][ar * 32 + pc * 8];
            }
            if (mh == 0) {   // B frags shared across the two M-half phases
#pragma unroll
                for (int j = 0; j < 4; ++j) {
                    const int br = wn * 64 + j * 16 + l16;
                    const int pc = quad ^ ((br >> 1) & 3);
                    b[j] = *(const f16x8*)&sB[par][kk][br * 32 + pc * 8];
                }
            }

            if (p == 0)      stage_unit(xh,  gm0, &sA[(kt + 1) & 1][1][0], kt + 1, 1, tid);
            else if (p == 1) stage_unit(mhi, gn0, &sB[(kt + 1) & 1][1][0], kt + 1, 1, tid);
            else if (p == 2) stage_unit(xh,  gm0, &sA[par][0][0],          kt + 2, 0, tid);
            else             stage_unit(mhi, gn0, &sB[par][0][0],          kt + 2, 0, tid);

            if (p == 3) asm volatile("s_waitcnt vmcnt(4)" ::: "memory");
            __builtin_amdgcn_s_barrier();
            asm volatile("s_waitcnt lgkmcnt(0)" ::: "memory");
            __builtin_amdgcn_sched_barrier(0);
            __builtin_amdgcn_s_setprio(1);
#pragma unroll
            for (int i = 0; i < 4; ++i)
#pragma unroll
                for (int j = 0; j < 4; ++j)
                    acc[mh * 4 + i][j] =
                        __builtin_amdgcn_mfma_f32_16x16x32_f16(a[i], b[j], acc[mh * 4 + i][j], 0, 0, 0);
            __builtin_amdgcn_s_setprio(0);
            __builtin_amdgcn_s_barrier();
        }
    }

    // epilogue: C/D layout col=l16+j*16, row=quad*4+r (verified r1/r2)
#pragma unroll
    for (int m = 0; m < 8; ++m) {
        const size_t row0 = gm0 + wm * 128 + m * 16 + quad * 4;
#pragma unroll
        for (int j = 0; j < 4; ++j) {
            const size_t col = gn0 + wn * 64 + j * 16 + l16;
#pragma unroll
            for (int r = 0; r < 4; ++r)
                sc[(row0 + r) * NCPAD + col] = (_Float16)acc[m][j][r];
        }
    }
}

// ---- kernel 2 (mid-tier fallback): round-5 fp32-A GEMM, verbatim -----------
__global__ __launch_bounds__(512, 4)
void gemm_f32a_kernel(const float* __restrict__ x,
                      const _Float16* __restrict__ mhi,
                      _Float16* __restrict__ sc)
{
    __shared__ float    sA [128 * 32];   // 16 KB
    __shared__ _Float16 sBh[256 * 32];   // 16 KB

    const int tid  = threadIdx.x;
    const int lane = tid & 63;
    const int w    = tid >> 6;           // 0..7
    const int wm   = w & 1;
    const int wn   = w >> 1;
    const int quad = lane >> 4, l16 = lane & 15;
    const size_t gm0 = (size_t)blockIdx.y * 128;
    const size_t gn0 = (size_t)blockIdx.x * 256;

    f32x4 acc[4][4] = {};

    for (int kt = 0; kt < ND / 32; ++kt) {
        const int k0 = kt * 32;
#pragma unroll
        for (int r = 0; r < 2; ++r) {
            const int slot = r * 512 + tid;
            const int arow = slot >> 3;
            const int ac   = (slot & 7) ^ (arow & 7);
            gl_lds16_f(x + ((gm0 + arow) << 11) + k0 + ac * 4,
                       &sA[(r * 512 + w * 64) * 4]);
            const int brow = slot >> 2;
            const int bc   = (slot & 3) ^ ((brow >> 1) & 3);
            gl_lds16_h(mhi + ((gn0 + brow) << 11) + k0 + bc * 8,
                       &sBh[(r * 512 + w * 64) * 8]);
        }
        __syncthreads();

        f16x8 ah[4], bh[4];
#pragma unroll
        for (int i = 0; i < 4; ++i) {
            const int ar = wm * 64 + i * 16 + l16;
            const int c1 = (2 * quad)     ^ (ar & 7);
            const int c2 = (2 * quad + 1) ^ (ar & 7);
            const f32x4 a0 = *(const f32x4*)&sA[ar * 32 + c1 * 4];
            const f32x4 a1 = *(const f32x4*)&sA[ar * 32 + c2 * 4];
            ah[i] = cvt8(a0, a1);
        }
#pragma unroll
        for (int j = 0; j < 4; ++j) {
            const int br = wn * 64 + j * 16 + l16;
            const int pc = quad ^ ((br >> 1) & 3);
            bh[j] = *(const f16x8*)&sBh[br * 32 + pc * 8];
        }
#pragma unroll
        for (int i = 0; i < 4; ++i)
#pragma unroll
            for (int j = 0; j < 4; ++j)
                acc[i][j] = __builtin_amdgcn_mfma_f32_16x16x32_f16(ah[i], bh[j], acc[i][j], 0, 0, 0);
        __syncthreads();
    }

#pragma unroll
    for (int i = 0; i < 4; ++i) {
        const size_t row0 = gm0 + wm * 64 + i * 16 + quad * 4;
#pragma unroll
        for (int j = 0; j < 4; ++j) {
            const size_t col = gn0 + wn * 64 + j * 16 + l16;
#pragma unroll
            for (int r = 0; r < 4; ++r)
                sc[(row0 + r) * NCPAD + col] = (_Float16)acc[i][j][r];
        }
    }
}

// ---- mid-tier means converter (round-5, verbatim) --------------------------
__global__ __launch_bounds__(256)
void cvt_m_kernel(const float* __restrict__ src, _Float16* __restrict__ hi)
{
    const int i = blockIdx.x * 256 + threadIdx.x;
    const int row = (i * 4) >> 11;
    float4 v = make_float4(0.f, 0.f, 0.f, 0.f);
    if (row < NC) v = ((const float4*)src)[i];
    f16x4 h;
    h[0] = (_Float16)v.x; h[1] = (_Float16)v.y;
    h[2] = (_Float16)v.z; h[3] = (_Float16)v.w;
    ((f16x4*)hi)[i] = h;
}

// ---- kernel 3: refine.  One wave per row.  Single-candidate fast path (the
// DELTA bound proves the lone candidate IS the exact argmax -> no dot, no
// x-row load).  Candidate iteration is ballot-driven.  UNCHANGED this round
// (isolating the GEMM schedule change; refine will surface in top-5 if it is
// the hidden non-GEMM cost). ------------------------------------------------
__global__ __launch_bounds__(256, 4)
void refine_kernel(const _Float16* __restrict__ sc,
                   const float* __restrict__ x,
                   const float* __restrict__ means,
                   float* __restrict__ out)
{
    const int lane = threadIdx.x & 63;
    const int row  = blockIdx.x * 4 + (threadIdx.x >> 6);

    // 16 approx scores per lane (whole 1024-wide row per wave)
    const f16x8* srow = (const f16x8*)(sc + (size_t)row * NCPAD + lane * 16);
    const f16x8 s0 = srow[0], s1 = srow[1];
    float v[16];
#pragma unroll
    for (int e = 0; e < 8; ++e) { v[e] = (float)s0[e]; v[8 + e] = (float)s1[e]; }

    float mx = -INFINITY;
#pragma unroll
    for (int e = 0; e < 16; ++e) {
        const int c = lane * 16 + e;
        if (c < NC && v[e] > mx) mx = v[e];
    }
#pragma unroll
    for (int off = 1; off < 64; off <<= 1) {
        const float o = __shfl_xor(mx, off);
        if (o > mx) mx = o;
    }
    const float T = mx - DELTA;

    unsigned cm = 0;
#pragma unroll
    for (int e = 0; e < 16; ++e) {
        const int c = lane * 16 + e;
        if (c < NC && v[e] >= T) cm |= (1u << e);
    }

    const unsigned long long bl = __ballot(cm != 0u);   // nonzero: max lane qualifies
    const int first  = (int)__builtin_ctzll(bl);
    const unsigned cmf = (unsigned)__shfl((int)cm, first);

    int bc;
    if (__builtin_popcountll(bl) == 1 && __builtin_popcount(cmf) == 1) {
        // exactly one candidate in the window -> it is the exact argmax
        bc = first * 16 + __builtin_ctz(cmf);
    } else {
        // slow path: preload x row (8 KB / 64 lanes = 32 fp32 per lane)
        const float* xrow = x + ((size_t)row << 11);
        f32x4 xr[8];
#pragma unroll
        for (int it = 0; it < 8; ++it)
            xr[it] = *(const f32x4*)(xrow + it * 256 + lane * 4);

        float bv = -INFINITY;
        bc = 0x7fffffff;
        unsigned long long pend = bl;
        while (pend) {
            const int src = (int)__builtin_ctzll(pend);
            pend &= pend - 1;
            unsigned cms = (unsigned)__shfl((int)cm, src);
            while (cms) {
                const int c = src * 16 + __builtin_ctz(cms);
                cms &= cms - 1;

                // exact fp32 dot(x[row], means[c]) — deterministic reduce order
                const float* mrow = means + ((size_t)c << 11);
                float part = 0.f;
#pragma unroll
                for (int it = 0; it < 8; ++it) {
                    const f32x4 mv = *(const f32x4*)(mrow + it * 256 + lane * 4);
                    part = fmaf(xr[it][0], mv[0], part);
                    part = fmaf(xr[it][1], mv[1], part);
                    part = fmaf(xr[it][2], mv[2], part);
                    part = fmaf(xr[it][3], mv[3], part);
                }
                float s = part;
#pragma unroll
                for (int off = 1; off < 64; off <<= 1) s += __shfl_xor(s, off);

                if (s > bv || (s == bv && c < bc)) { bv = s; bc = c; }  // first-index ties
            }
        }
    }

    float4* orow = (float4*)(out + (size_t)row * NC);
#pragma unroll
    for (int i = 0; i < 4; ++i) {
        const int idx = lane + i * 64;
        if (idx < NC / 4) {
            const int cb = idx * 4;
            float4 ov;
            ov.x = (cb     == bc) ? 1.f : 0.f;
            ov.y = (cb + 1 == bc) ? 1.f : 0.f;
            ov.z = (cb + 2 == bc) ? 1.f : 0.f;
            ov.w = (cb + 3 == bc) ? 1.f : 0.f;
            orow[idx] = ov;
        }
    }
}

// ===========================================================================
// Fallback: round-1 fp32 LDS-tiled kernel (correct, ~1.9 ms) if ws too small.
// ===========================================================================
#define MS 64
#define CS 256
#define KT 32
#define NCHUNK 4

__global__ __launch_bounds__(256, 1)
void nnc_fp32_kernel(const float* __restrict__ x,
                     const float* __restrict__ means,
                     float* __restrict__ out)
{
    __shared__ float xs[MS * KT];
    __shared__ float msh[CS * KT];
    __shared__ float rbest[MS * 33];
    __shared__ int   ridx[MS * 33];
    __shared__ int   widx[MS];

    const int tid = threadIdx.x;
    const int tx  = tid & 31;
    const int ty  = tid >> 5;
    const int s0  = blockIdx.x * MS;
    const int m0  = ty * 8;
    const int cL  = tx * 8;

    float best[8];
    int   bidx[8];
#pragma unroll
    for (int i = 0; i < 8; ++i) { best[i] = -INFINITY; bidx[i] = 0; }

    const int kslot = tid & 7;
    const int rrow  = tid >> 3;

    for (int chunk = 0; chunk < NCHUNK; ++chunk) {
        const int c0 = chunk * CS;
        float acc[8][8];
#pragma unroll
        for (int i = 0; i < 8; ++i)
#pragma unroll
            for (int j = 0; j < 8; ++j) acc[i][j] = 0.0f;

        for (int k0 = 0; k0 < ND; k0 += KT) {
#pragma unroll
            for (int r = 0; r < 2; ++r) {
                const int m = rrow + r * 32;
                const float4 v = *(const float4*)(x + (size_t)(s0 + m) * ND + k0 + kslot * 4);
                *(float4*)(xs + m * KT + kslot * 4) = v;
            }
#pragma unroll
            for (int r = 0; r < 8; ++r) {
                const int c  = rrow + r * 32;
                const int cg = c0 + c;
                float4 v = make_float4(0.f, 0.f, 0.f, 0.f);
                if (cg < NC) v = *(const float4*)(means + (size_t)cg * ND + k0 + kslot * 4);
                const int pslot = (kslot + (c >> 3)) & 7;
                *(float4*)(msh + c * KT + pslot * 4) = v;
            }
            __syncthreads();
#pragma unroll
            for (int k4 = 0; k4 < KT / 4; ++k4) {
                float4 a[8], b[8];
                const int boff = ((k4 + tx) & 7) * 4;
#pragma unroll
                for (int i = 0; i < 8; ++i) a[i] = *(const float4*)(xs + (m0 + i) * KT + k4 * 4);
#pragma unroll
                for (int j = 0; j < 8; ++j) b[j] = *(const float4*)(msh + (cL + j) * KT + boff);
#pragma unroll
                for (int i = 0; i < 8; ++i)
#pragma unroll
                    for (int j = 0; j < 8; ++j) {
                        acc[i][j] = fmaf(a[i].x, b[j].x, acc[i][j]);
                        acc[i][j] = fmaf(a[i].y, b[j].y, acc[i][j]);
                        acc[i][j] = fmaf(a[i].z, b[j].z, acc[i][j]);
                        acc[i][j] = fmaf(a[i].w, b[j].w, acc[i][j]);
                    }
            }
            __syncthreads();
        }
#pragma unroll
        for (int i = 0; i < 8; ++i)
#pragma unroll
            for (int j = 0; j < 8; ++j) {
                const int c = c0 + cL + j;
                const float v = acc[i][j];
                if (c < NC && (v > best[i] || (v == best[i] && c < bidx[i]))) {
                    best[i] = v; bidx[i] = c;
                }
            }
    }
#pragma unroll
    for (int i = 0; i < 8; ++i) {
        rbest[(m0 + i) * 33 + tx] = best[i];
        ridx[(m0 + i) * 33 + tx]  = bidx[i];
    }
    __syncthreads();
    if (tid < MS) {
        float bv = rbest[tid * 33];
        int   bc = ridx[tid * 33];
        for (int t = 1; t < 32; ++t) {
            const float v = rbest[tid * 33 + t];
            const int   c = ridx[tid * 33 + t];
            if (v > bv || (v == bv && c < bc)) { bv = v; bc = c; }
        }
        widx[tid] = bc;
    }
    __syncthreads();
    if (tid < 250) {
        const int cbase = tid * 4;
        for (int m = 0; m < MS; ++m) {
            const int w = widx[m];
            float4 v;
            v.x = (cbase == w) ? 1.f : 0.f;
            v.y = (cbase + 1 == w) ? 1.f : 0.f;
            v.z = (cbase + 2 == w) ? 1.f : 0.f;
            v.w = (cbase + 3 == w) ? 1.f : 0.f;
            *(float4*)(out + (size_t)(s0 + m) * NC + cbase) = v;
        }
    }
}

extern "C" void kernel_launch(void* const* d_in, const int* in_sizes, int n_in,
                              void* d_out, int out_size, void* d_ws, size_t ws_size,
                              hipStream_t stream) {
    const float* x     = (const float*)d_in[0];
    const float* means = (const float*)d_in[1];
    float* out         = (float*)d_out;

    if (ws_size >= WS_NEW) {
        char* ws = (char*)d_ws;
        _Float16* mhi = (_Float16*)ws;                         // 4 MB
        _Float16* xh  = (_Float16*)(ws + (4ull  << 20));       // 64 MB
        _Float16* sc  = (_Float16*)(ws + (68ull << 20));       // 32 MB

        cvt_all_kernel<<<dim3((NCPAD * ND / 4 + NS * ND / 4) / 256), dim3(256), 0, stream>>>(x, means, xh, mhi);
        gemm256_kernel<<<dim3(NCPAD / 256, NS / 256), dim3(512), 0, stream>>>(xh, mhi, sc);
        refine_kernel<<<dim3(NS / 4), dim3(256), 0, stream>>>(sc, x, means, out);
    } else if (ws_size >= WS_MID) {
        char* ws = (char*)d_ws;
        _Float16* mhi = (_Float16*)ws;
        _Float16* sc  = (_Float16*)(ws + 4194304ull);

        cvt_m_kernel<<<dim3(NCPAD * ND / 4 / 256), dim3(256), 0, stream>>>(means, mhi);
        gemm_f32a_kernel<<<dim3(NCPAD / 256, NS / 128), dim3(512), 0, stream>>>(x, mhi, sc);
        refine_kernel<<<dim3(NS / 4), dim3(256), 0, stream>>>(sc, x, means, out);
    } else {
        nnc_fp32_kernel<<<dim3(NS / MS), dim3(256), 0, stream>>>(x, means, out);
    }
}

// Round 5
// 301.791 us; speedup vs baseline: 1.0194x; 1.0194x over previous
//
#include <hip/hip_runtime.h>
#include <math.h>

// Problem shape (fixed by the bench's setup_inputs)
#define NS 16384
#define ND 2048
#define NC 1000
#define NCPAD 1024

typedef _Float16 f16x8 __attribute__((ext_vector_type(8)));
typedef _Float16 f16x4 __attribute__((ext_vector_type(4)));
typedef __fp16   h16x2 __attribute__((ext_vector_type(2)));
typedef float f32x4  __attribute__((ext_vector_type(4)));

// Candidate window: must exceed 2*E where E bounds |approx - exact| per score.
// E <= 10-sigma of sum-of-2048 f16-product errors (~0.44) + f16 store round
// (<=0.11) => 2E ~ 1.1.  Delta = 2.5 gives >2x margin.
#define DELTA 2.5f

// Fast path: mhi 4MB + xh 64MB + sc 32MB = 100 MB
#define WS_NEW 104857600ull
// Mid-tier path: mhi 4MB + sc 32MB
#define WS_MID 37748736ull

__device__ __forceinline__ void gl_lds16_h(const _Float16* g, _Float16* l) {
    __builtin_amdgcn_global_load_lds(
        (const __attribute__((address_space(1))) unsigned int*)g,
        (__attribute__((address_space(3))) unsigned int*)l, 16, 0, 0);
}
__device__ __forceinline__ void gl_lds16_f(const float* g, float* l) {
    __builtin_amdgcn_global_load_lds(
        (const __attribute__((address_space(1))) unsigned int*)g,
        (__attribute__((address_space(3))) unsigned int*)l, 16, 0, 0);
}

// fp32x8 -> f16x8 (RTZ pack) — used only by the mid-tier fallback GEMM
__device__ __forceinline__ f16x8 cvt8(const f32x4 a0, const f32x4 a1) {
    const h16x2 h01 = __builtin_amdgcn_cvt_pkrtz(a0[0], a0[1]);
    const h16x2 h23 = __builtin_amdgcn_cvt_pkrtz(a0[2], a0[3]);
    const h16x2 h45 = __builtin_amdgcn_cvt_pkrtz(a1[0], a1[1]);
    const h16x2 h67 = __builtin_amdgcn_cvt_pkrtz(a1[2], a1[3]);
    f16x8 h;
    h[0]=(_Float16)h01[0]; h[1]=(_Float16)h01[1]; h[2]=(_Float16)h23[0]; h[3]=(_Float16)h23[1];
    h[4]=(_Float16)h45[0]; h[5]=(_Float16)h45[1]; h[6]=(_Float16)h67[0]; h[7]=(_Float16)h67[1];
    return h;
}

// ---- kernel 1: fused fp32->f16 (RN) conversion of means (zero-padded to
// NCPAD rows) AND x.  Pure-BW kernel, ~196 MB traffic. ----------------------
__global__ __launch_bounds__(256)
void cvt_all_kernel(const float* __restrict__ x, const float* __restrict__ means,
                    _Float16* __restrict__ xh, _Float16* __restrict__ mhi)
{
    const size_t i = (size_t)blockIdx.x * 256 + threadIdx.x;  // float4 slot
    const size_t NM4 = (size_t)NCPAD * ND / 4;                // 524288
    if (i < NM4) {
        const int row = (int)(i >> 9);                        // (i*4)/ND
        float4 v = make_float4(0.f, 0.f, 0.f, 0.f);
        if (row < NC) v = ((const float4*)means)[i];
        f16x4 h;
        h[0]=(_Float16)v.x; h[1]=(_Float16)v.y; h[2]=(_Float16)v.z; h[3]=(_Float16)v.w;
        ((f16x4*)mhi)[i] = h;
    } else {
        const size_t j = i - NM4;                             // < NS*ND/4
        const float4 v = ((const float4*)x)[j];
        f16x4 h;
        h[0]=(_Float16)v.x; h[1]=(_Float16)v.y; h[2]=(_Float16)v.z; h[3]=(_Float16)v.w;
        ((f16x4*)xh)[j] = h;
    }
}

// ============================================================================
// kernel 2: 256x256 f16 MFMA GEMM, 2-barriers-per-K-tile deep pipeline.
//
// r4 post-mortem: 8 lockstep barriers/tile serialize the LDS-read section and
// the MFMA section (phase = ~1519 cyc, MFMA pipe = 515 -> 34% MfmaUtil).  All
// of tile t's LDS (kk0+kk1) is validated by the single vmcnt(4)+barrier at
// tile open, so intra-tile barriers are only needed for stage-WAR:
//   open barrier -> [reads kk0 (12 b128) + reads kk1-A (8) + stage u0,u1
//   (t+1 kk1) ; 32 MFMA kk0 (compiler emits counted lgkmcnt(8): kk1-A reads
//   complete UNDER the kk0 cluster)] -> mid barrier (all waves' kk0 reads
//   retired) -> [reads kk1-B (4) + stage u2,u3 (t+2 kk0 into the now-dead kk0
//   region) ; 32 MFMA kk1] -> vmcnt(4) -> end barrier.
//
// vmcnt ledger at end of tile t (units of 2 loads, oldest->newest):
//   (t-1).u2[(t+1)Ak0], (t-1).u3[(t+1)Bk0], t.u0[(t+1)Ak1], t.u1[(t+1)Bk1],
//   t.u2[(t+2)Ak0], t.u3[(t+2)Bk0] = 12 loads; vmcnt(4) completes the 8
//   oldest = ALL of tile t+1 before its open barrier.  Prologue primes 6
//   units then vmcnt(4) (tile 0 resident, 2 units outstanding = steady state).
// WAR: u0/u1 write t-1's kk1 regions (reads retired before t-1's end barrier);
//   u2/u3 write t's kk0 regions (reads retired before this tile's mid barrier,
//   each wave's auto-lgkmcnt precedes its kk0 MFMAs which precede the barrier).
// Tail: stage source K-tile CLAMPED to 31; clamped stages land only in dead
//   regions (checked per-region; never read again).
// Fragment/epilogue layout identical to the r1-r4-verified kernels.
// __launch_bounds__(512,2) caps VGPR at 256 so the 8-wave block stays
// resident at 2 waves/SIMD (peak live ~240).
// ============================================================================
__device__ __forceinline__ void stage_unit(const _Float16* __restrict__ src,
                                           size_t g0, _Float16* dstbase,
                                           int ktile, int kkh, int tid)
{
    const int srcT = ktile < 31 ? ktile : 31;   // clamp: dead-region safe
#pragma unroll
    for (int q = 0; q < 2; ++q) {
        const int slot = q * 512 + tid;          // 0..1023 (16B chunks)
        const int row  = slot >> 2;              // 0..255
        const int g    = (slot & 3) ^ ((row >> 1) & 3);
        gl_lds16_h(src + ((g0 + (size_t)row) << 11) + srcT * 64 + kkh * 32 + g * 8,
                   dstbase + (size_t)(q * 512 + ((tid >> 6) << 6)) * 8);
    }
}

__global__ __launch_bounds__(512, 2)
void gemm256_kernel(const _Float16* __restrict__ xh,
                    const _Float16* __restrict__ mhi,
                    _Float16* __restrict__ sc)
{
    __shared__ _Float16 sA[2][2][256 * 32];   // [par][kk] 64 KB
    __shared__ _Float16 sB[2][2][256 * 32];   // 64 KB

    const int tid  = threadIdx.x;
    const int lane = tid & 63;
    const int w    = tid >> 6;           // 0..7
    const int wm   = w >> 2;             // 0..1 (M half)
    const int wn   = w & 3;              // 0..3 (N quarter)
    const int quad = lane >> 4, l16 = lane & 15;

    // XCD-bijective swizzle: grid (4,64) -> 256 blocks, 32 per XCD,
    // each XCD gets 8 contiguous row-panels x all 4 col-tiles.
    const int orig = blockIdx.x + (blockIdx.y << 2);
    const int nid  = ((orig & 7) << 5) + (orig >> 3);
    const size_t gm0 = (size_t)(nid >> 2) * 256;   // sample rows
    const size_t gn0 = (size_t)(nid & 3) * 256;    // class cols

    f32x4 acc[8][4] = {};

    // prologue: ages must match steady stream
    stage_unit(xh,  gm0, &sA[0][0][0], 0, 0, tid);
    stage_unit(mhi, gn0, &sB[0][0][0], 0, 0, tid);
    stage_unit(xh,  gm0, &sA[0][1][0], 0, 1, tid);
    stage_unit(mhi, gn0, &sB[0][1][0], 0, 1, tid);
    stage_unit(xh,  gm0, &sA[1][0][0], 1, 0, tid);
    stage_unit(mhi, gn0, &sB[1][0][0], 1, 0, tid);
    asm volatile("s_waitcnt vmcnt(4)" ::: "memory");
    __builtin_amdgcn_s_barrier();

    for (int kt = 0; kt < 32; ++kt) {
        const int par = kt & 1;

        // ---- first half: read kk0 (12) + prefetch kk1-A (8), stage t+1.kk1,
        //      then 32 MFMAs on kk0 (auto lgkmcnt(8) lets kk1-A fly under) ---
        f16x8 a0[4], a1[4], b0[4], c0[4], c1[4];
#pragma unroll
        for (int i = 0; i < 4; ++i) {
            const int r0 = wm * 128 + i * 16 + l16;
            const int r1 = r0 + 64;
            const int p0 = quad ^ ((r0 >> 1) & 3);
            const int p1 = quad ^ ((r1 >> 1) & 3);
            a0[i] = *(const f16x8*)&sA[par][0][r0 * 32 + p0 * 8];
            a1[i] = *(const f16x8*)&sA[par][0][r1 * 32 + p1 * 8];
        }
#pragma unroll
        for (int j = 0; j < 4; ++j) {
            const int br = wn * 64 + j * 16 + l16;
            const int pc = quad ^ ((br >> 1) & 3);
            b0[j] = *(const f16x8*)&sB[par][0][br * 32 + pc * 8];
        }
#pragma unroll
        for (int i = 0; i < 4; ++i) {
            const int r0 = wm * 128 + i * 16 + l16;
            const int r1 = r0 + 64;
            const int p0 = quad ^ ((r0 >> 1) & 3);
            const int p1 = quad ^ ((r1 >> 1) & 3);
            c0[i] = *(const f16x8*)&sA[par][1][r0 * 32 + p0 * 8];
            c1[i] = *(const f16x8*)&sA[par][1][r1 * 32 + p1 * 8];
        }
        stage_unit(xh,  gm0, &sA[(kt + 1) & 1][1][0], kt + 1, 1, tid);
        stage_unit(mhi, gn0, &sB[(kt + 1) & 1][1][0], kt + 1, 1, tid);
        __builtin_amdgcn_sched_barrier(0);
        __builtin_amdgcn_s_setprio(1);
#pragma unroll
        for (int i = 0; i < 4; ++i)
#pragma unroll
            for (int j = 0; j < 4; ++j)
                acc[i][j] = __builtin_amdgcn_mfma_f32_16x16x32_f16(a0[i], b0[j], acc[i][j], 0, 0, 0);
#pragma unroll
        for (int i = 0; i < 4; ++i)
#pragma unroll
            for (int j = 0; j < 4; ++j)
                acc[4 + i][j] = __builtin_amdgcn_mfma_f32_16x16x32_f16(a1[i], b0[j], acc[4 + i][j], 0, 0, 0);
        __builtin_amdgcn_s_setprio(0);
        __builtin_amdgcn_s_barrier();   // mid: all waves' kk0 reads retired

        // ---- second half: read kk1-B (4), stage t+2.kk0 into dead kk0
        //      region, 32 MFMAs on kk1, single counted vmcnt, end barrier ----
        f16x8 b1[4];
#pragma unroll
        for (int j = 0; j < 4; ++j) {
            const int br = wn * 64 + j * 16 + l16;
            const int pc = quad ^ ((br >> 1) & 3);
            b1[j] = *(const f16x8*)&sB[par][1][br * 32 + pc * 8];
        }
        stage_unit(xh,  gm0, &sA[par][0][0], kt + 2, 0, tid);
        stage_unit(mhi, gn0, &sB[par][0][0], kt + 2, 0, tid);
        __builtin_amdgcn_sched_barrier(0);
        __builtin_amdgcn_s_setprio(1);
#pragma unroll
        for (int i = 0; i < 4; ++i)
#pragma unroll
            for (int j = 0; j < 4; ++j)
                acc[i][j] = __builtin_amdgcn_mfma_f32_16x16x32_f16(c0[i], b1[j], acc[i][j], 0, 0, 0);
#pragma unroll
        for (int i = 0; i < 4; ++i)
#pragma unroll
            for (int j = 0; j < 4; ++j)
                acc[4 + i][j] = __builtin_amdgcn_mfma_f32_16x16x32_f16(c1[i], b1[j], acc[4 + i][j], 0, 0, 0);
        __builtin_amdgcn_s_setprio(0);
        asm volatile("s_waitcnt vmcnt(4)" ::: "memory");
        __builtin_amdgcn_s_barrier();   // end: opens tile t+1
    }

    // epilogue: C/D layout col=l16+j*16, row=quad*4+r (verified r1-r4)
#pragma unroll
    for (int m = 0; m < 8; ++m) {
        const size_t row0 = gm0 + wm * 128 + m * 16 + quad * 4;
#pragma unroll
        for (int j = 0; j < 4; ++j) {
            const size_t col = gn0 + wn * 64 + j * 16 + l16;
#pragma unroll
            for (int r = 0; r < 4; ++r)
                sc[(row0 + r) * NCPAD + col] = (_Float16)acc[m][j][r];
        }
    }
}

// ---- kernel 2 (mid-tier fallback): round-5 fp32-A GEMM, verbatim -----------
__global__ __launch_bounds__(512, 4)
void gemm_f32a_kernel(const float* __restrict__ x,
                      const _Float16* __restrict__ mhi,
                      _Float16* __restrict__ sc)
{
    __shared__ float    sA [128 * 32];   // 16 KB
    __shared__ _Float16 sBh[256 * 32];   // 16 KB

    const int tid  = threadIdx.x;
    const int lane = tid & 63;
    const int w    = tid >> 6;           // 0..7
    const int wm   = w & 1;
    const int wn   = w >> 1;
    const int quad = lane >> 4, l16 = lane & 15;
    const size_t gm0 = (size_t)blockIdx.y * 128;
    const size_t gn0 = (size_t)blockIdx.x * 256;

    f32x4 acc[4][4] = {};

    for (int kt = 0; kt < ND / 32; ++kt) {
        const int k0 = kt * 32;
#pragma unroll
        for (int r = 0; r < 2; ++r) {
            const int slot = r * 512 + tid;
            const int arow = slot >> 3;
            const int ac   = (slot & 7) ^ (arow & 7);
            gl_lds16_f(x + ((gm0 + arow) << 11) + k0 + ac * 4,
                       &sA[(r * 512 + w * 64) * 4]);
            const int brow = slot >> 2;
            const int bc   = (slot & 3) ^ ((brow >> 1) & 3);
            gl_lds16_h(mhi + ((gn0 + brow) << 11) + k0 + bc * 8,
                       &sBh[(r * 512 + w * 64) * 8]);
        }
        __syncthreads();

        f16x8 ah[4], bh[4];
#pragma unroll
        for (int i = 0; i < 4; ++i) {
            const int ar = wm * 64 + i * 16 + l16;
            const int c1 = (2 * quad)     ^ (ar & 7);
            const int c2 = (2 * quad + 1) ^ (ar & 7);
            const f32x4 a0 = *(const f32x4*)&sA[ar * 32 + c1 * 4];
            const f32x4 a1 = *(const f32x4*)&sA[ar * 32 + c2 * 4];
            ah[i] = cvt8(a0, a1);
        }
#pragma unroll
        for (int j = 0; j < 4; ++j) {
            const int br = wn * 64 + j * 16 + l16;
            const int pc = quad ^ ((br >> 1) & 3);
            bh[j] = *(const f16x8*)&sBh[br * 32 + pc * 8];
        }
#pragma unroll
        for (int i = 0; i < 4; ++i)
#pragma unroll
            for (int j = 0; j < 4; ++j)
                acc[i][j] = __builtin_amdgcn_mfma_f32_16x16x32_f16(ah[i], bh[j], acc[i][j], 0, 0, 0);
        __syncthreads();
    }

#pragma unroll
    for (int i = 0; i < 4; ++i) {
        const size_t row0 = gm0 + wm * 64 + i * 16 + quad * 4;
#pragma unroll
        for (int j = 0; j < 4; ++j) {
            const size_t col = gn0 + wn * 64 + j * 16 + l16;
#pragma unroll
            for (int r = 0; r < 4; ++r)
                sc[(row0 + r) * NCPAD + col] = (_Float16)acc[i][j][r];
        }
    }
}

// ---- mid-tier means converter (round-5, verbatim) --------------------------
__global__ __launch_bounds__(256)
void cvt_m_kernel(const float* __restrict__ src, _Float16* __restrict__ hi)
{
    const int i = blockIdx.x * 256 + threadIdx.x;
    const int row = (i * 4) >> 11;
    float4 v = make_float4(0.f, 0.f, 0.f, 0.f);
    if (row < NC) v = ((const float4*)src)[i];
    f16x4 h;
    h[0] = (_Float16)v.x; h[1] = (_Float16)v.y;
    h[2] = (_Float16)v.z; h[3] = (_Float16)v.w;
    ((f16x4*)hi)[i] = h;
}

// ---- kernel 3: refine.  One wave per row.  Single-candidate fast path (the
// DELTA bound proves the lone candidate IS the exact argmax -> no dot, no
// x-row load).  Candidate iteration is ballot-driven.  UNCHANGED this round.
__global__ __launch_bounds__(256, 4)
void refine_kernel(const _Float16* __restrict__ sc,
                   const float* __restrict__ x,
                   const float* __restrict__ means,
                   float* __restrict__ out)
{
    const int lane = threadIdx.x & 63;
    const int row  = blockIdx.x * 4 + (threadIdx.x >> 6);

    // 16 approx scores per lane (whole 1024-wide row per wave)
    const f16x8* srow = (const f16x8*)(sc + (size_t)row * NCPAD + lane * 16);
    const f16x8 s0 = srow[0], s1 = srow[1];
    float v[16];
#pragma unroll
    for (int e = 0; e < 8; ++e) { v[e] = (float)s0[e]; v[8 + e] = (float)s1[e]; }

    float mx = -INFINITY;
#pragma unroll
    for (int e = 0; e < 16; ++e) {
        const int c = lane * 16 + e;
        if (c < NC && v[e] > mx) mx = v[e];
    }
#pragma unroll
    for (int off = 1; off < 64; off <<= 1) {
        const float o = __shfl_xor(mx, off);
        if (o > mx) mx = o;
    }
    const float T = mx - DELTA;

    unsigned cm = 0;
#pragma unroll
    for (int e = 0; e < 16; ++e) {
        const int c = lane * 16 + e;
        if (c < NC && v[e] >= T) cm |= (1u << e);
    }

    const unsigned long long bl = __ballot(cm != 0u);   // nonzero: max lane qualifies
    const int first  = (int)__builtin_ctzll(bl);
    const unsigned cmf = (unsigned)__shfl((int)cm, first);

    int bc;
    if (__builtin_popcountll(bl) == 1 && __builtin_popcount(cmf) == 1) {
        // exactly one candidate in the window -> it is the exact argmax
        bc = first * 16 + __builtin_ctz(cmf);
    } else {
        // slow path: preload x row (8 KB / 64 lanes = 32 fp32 per lane)
        const float* xrow = x + ((size_t)row << 11);
        f32x4 xr[8];
#pragma unroll
        for (int it = 0; it < 8; ++it)
            xr[it] = *(const f32x4*)(xrow + it * 256 + lane * 4);

        float bv = -INFINITY;
        bc = 0x7fffffff;
        unsigned long long pend = bl;
        while (pend) {
            const int src = (int)__builtin_ctzll(pend);
            pend &= pend - 1;
            unsigned cms = (unsigned)__shfl((int)cm, src);
            while (cms) {
                const int c = src * 16 + __builtin_ctz(cms);
                cms &= cms - 1;

                // exact fp32 dot(x[row], means[c]) — deterministic reduce order
                const float* mrow = means + ((size_t)c << 11);
                float part = 0.f;
#pragma unroll
                for (int it = 0; it < 8; ++it) {
                    const f32x4 mv = *(const f32x4*)(mrow + it * 256 + lane * 4);
                    part = fmaf(xr[it][0], mv[0], part);
                    part = fmaf(xr[it][1], mv[1], part);
                    part = fmaf(xr[it][2], mv[2], part);
                    part = fmaf(xr[it][3], mv[3], part);
                }
                float s = part;
#pragma unroll
                for (int off = 1; off < 64; off <<= 1) s += __shfl_xor(s, off);

                if (s > bv || (s == bv && c < bc)) { bv = s; bc = c; }  // first-index ties
            }
        }
    }

    float4* orow = (float4*)(out + (size_t)row * NC);
#pragma unroll
    for (int i = 0; i < 4; ++i) {
        const int idx = lane + i * 64;
        if (idx < NC / 4) {
            const int cb = idx * 4;
            float4 ov;
            ov.x = (cb     == bc) ? 1.f : 0.f;
            ov.y = (cb + 1 == bc) ? 1.f : 0.f;
            ov.z = (cb + 2 == bc) ? 1.f : 0.f;
            ov.w = (cb + 3 == bc) ? 1.f : 0.f;
            orow[idx] = ov;
        }
    }
}

// ===========================================================================
// Fallback: round-1 fp32 LDS-tiled kernel (correct, ~1.9 ms) if ws too small.
// ===========================================================================
#define MS 64
#define CS 256
#define KT 32
#define NCHUNK 4

__global__ __launch_bounds__(256, 1)
void nnc_fp32_kernel(const float* __restrict__ x,
                     const float* __restrict__ means,
                     float* __restrict__ out)
{
    __shared__ float xs[MS * KT];
    __shared__ float msh[CS * KT];
    __shared__ float rbest[MS * 33];
    __shared__ int   ridx[MS * 33];
    __shared__ int   widx[MS];

    const int tid = threadIdx.x;
    const int tx  = tid & 31;
    const int ty  = tid >> 5;
    const int s0  = blockIdx.x * MS;
    const int m0  = ty * 8;
    const int cL  = tx * 8;

    float best[8];
    int   bidx[8];
#pragma unroll
    for (int i = 0; i < 8; ++i) { best[i] = -INFINITY; bidx[i] = 0; }

    const int kslot = tid & 7;
    const int rrow  = tid >> 3;

    for (int chunk = 0; chunk < NCHUNK; ++chunk) {
        const int c0 = chunk * CS;
        float acc[8][8];
#pragma unroll
        for (int i = 0; i < 8; ++i)
#pragma unroll
            for (int j = 0; j < 8; ++j) acc[i][j] = 0.0f;

        for (int k0 = 0; k0 < ND; k0 += KT) {
#pragma unroll
            for (int r = 0; r < 2; ++r) {
                const int m = rrow + r * 32;
                const float4 v = *(const float4*)(x + (size_t)(s0 + m) * ND + k0 + kslot * 4);
                *(float4*)(xs + m * KT + kslot * 4) = v;
            }
#pragma unroll
            for (int r = 0; r < 8; ++r) {
                const int c  = rrow + r * 32;
                const int cg = c0 + c;
                float4 v = make_float4(0.f, 0.f, 0.f, 0.f);
                if (cg < NC) v = *(const float4*)(means + (size_t)cg * ND + k0 + kslot * 4);
                const int pslot = (kslot + (c >> 3)) & 7;
                *(float4*)(msh + c * KT + pslot * 4) = v;
            }
            __syncthreads();
#pragma unroll
            for (int k4 = 0; k4 < KT / 4; ++k4) {
                float4 a[8], b[8];
                const int boff = ((k4 + tx) & 7) * 4;
#pragma unroll
                for (int i = 0; i < 8; ++i) a[i] = *(const float4*)(xs + (m0 + i) * KT + k4 * 4);
#pragma unroll
                for (int j = 0; j < 8; ++j) b[j] = *(const float4*)(msh + (cL + j) * KT + boff);
#pragma unroll
                for (int i = 0; i < 8; ++i)
#pragma unroll
                    for (int j = 0; j < 8; ++j) {
                        acc[i][j] = fmaf(a[i].x, b[j].x, acc[i][j]);
                        acc[i][j] = fmaf(a[i].y, b[j].y, acc[i][j]);
                        acc[i][j] = fmaf(a[i].z, b[j].z, acc[i][j]);
                        acc[i][j] = fmaf(a[i].w, b[j].w, acc[i][j]);
                    }
            }
            __syncthreads();
        }
#pragma unroll
        for (int i = 0; i < 8; ++i)
#pragma unroll
            for (int j = 0; j < 8; ++j) {
                const int c = c0 + cL + j;
                const float v = acc[i][j];
                if (c < NC && (v > best[i] || (v == best[i] && c < bidx[i]))) {
                    best[i] = v; bidx[i] = c;
                }
            }
    }
#pragma unroll
    for (int i = 0; i < 8; ++i) {
        rbest[(m0 + i) * 33 + tx] = best[i];
        ridx[(m0 + i) * 33 + tx]  = bidx[i];
    }
    __syncthreads();
    if (tid < MS) {
        float bv = rbest[tid * 33];
        int   bc = ridx[tid * 33];
        for (int t = 1; t < 32; ++t) {
            const float v = rbest[tid * 33 + t];
            const int   c = ridx[tid * 33 + t];
            if (v > bv || (v == bv && c < bc)) { bv = v; bc = c; }
        }
        widx[tid] = bc;
    }
    __syncthreads();
    if (tid < 250) {
        const int cbase = tid * 4;
        for (int m = 0; m < MS; ++m) {
            const int w = widx[m];
            float4 v;
            v.x = (cbase == w) ? 1.f : 0.f;
            v.y = (cbase + 1 == w) ? 1.f : 0.f;
            v.z = (cbase + 2 == w) ? 1.f : 0.f;
            v.w = (cbase + 3 == w) ? 1.f : 0.f;
            *(float4*)(out + (size_t)(s0 + m) * NC + cbase) = v;
        }
    }
}

extern "C" void kernel_launch(void* const* d_in, const int* in_sizes, int n_in,
                              void* d_out, int out_size, void* d_ws, size_t ws_size,
                              hipStream_t stream) {
    const float* x     = (const float*)d_in[0];
    const float* means = (const float*)d_in[1];
    float* out         = (float*)d_out;

    if (ws_size >= WS_NEW) {
        char* ws = (char*)d_ws;
        _Float16* mhi = (_Float16*)ws;                         // 4 MB
        _Float16* xh  = (_Float16*)(ws + (4ull  << 20));       // 64 MB
        _Float16* sc  = (_Float16*)(ws + (68ull << 20));       // 32 MB

        cvt_all_kernel<<<dim3((NCPAD * ND / 4 + NS * ND / 4) / 256), dim3(256), 0, stream>>>(x, means, xh, mhi);
        gemm256_kernel<<<dim3(NCPAD / 256, NS / 256), dim3(512), 0, stream>>>(xh, mhi, sc);
        refine_kernel<<<dim3(NS / 4), dim3(256), 0, stream>>>(sc, x, means, out);
    } else if (ws_size >= WS_MID) {
        char* ws = (char*)d_ws;
        _Float16* mhi = (_Float16*)ws;
        _Float16* sc  = (_Float16*)(ws + 4194304ull);

        cvt_m_kernel<<<dim3(NCPAD * ND / 4 / 256), dim3(256), 0, stream>>>(means, mhi);
        gemm_f32a_kernel<<<dim3(NCPAD / 256, NS / 128), dim3(512), 0, stream>>>(x, mhi, sc);
        refine_kernel<<<dim3(NS / 4), dim3(256), 0, stream>>>(sc, x, means, out);
    } else {
        nnc_fp32_kernel<<<dim3(NS / MS), dim3(256), 0, stream>>>(x, means, out);
    }
}